// Round 1
// baseline (262.000 us; speedup 1.0000x reference)
//
#include <hip/hip_runtime.h>
#include <hip/hip_bf16.h>

typedef __bf16 bf16;
typedef __bf16 bf16x8 __attribute__((ext_vector_type(8)));
typedef __bf16 bf16x4 __attribute__((ext_vector_type(4)));
typedef float  f32x4  __attribute__((ext_vector_type(4)));

#define LOG2E 1.44269504088896340736f

// Problem constants
// B=2, S=2048, C=1024, H=16, D=64, 3C=3072, M=B*S=4096

__device__ __forceinline__ void gl_lds16(const void* g, void* l) {
  __builtin_amdgcn_global_load_lds((__attribute__((address_space(1))) void*)g,
                                   (__attribute__((address_space(3))) void*)l,
                                   16, 0, 0);
}

// ---------------------------------------------------------------------------
// fp32 -> bf16 conversion for x, w1 (in_proj), w2 (out_proj)
// ---------------------------------------------------------------------------
__global__ void cvt3_kernel(const float* __restrict__ x,
                            const float* __restrict__ w1,
                            const float* __restrict__ w2,
                            bf16* __restrict__ xb,
                            bf16* __restrict__ w1b,
                            bf16* __restrict__ w2b) {
  const int NX = 1048576, NW1 = 786432, NW2 = 262144; // in float4 quads
  const int total = NX + NW1 + NW2;
  int i = blockIdx.x * blockDim.x + threadIdx.x;
  const int stride = gridDim.x * blockDim.x;
  for (; i < total; i += stride) {
    const float* s; bf16* d; int j;
    if (i < NX)            { s = x;  d = xb;  j = i; }
    else if (i < NX + NW1) { s = w1; d = w1b; j = i - NX; }
    else                   { s = w2; d = w2b; j = i - NX - NW1; }
    f32x4 v = ((const f32x4*)s)[j];
    bf16x4 o;
    o[0] = (bf16)v[0]; o[1] = (bf16)v[1]; o[2] = (bf16)v[2]; o[3] = (bf16)v[3];
    ((bf16x4*)d)[j] = o;
  }
}

// ---------------------------------------------------------------------------
// GEMM: C[m][n] = sum_k A[m][k] * Bw[n][k] + bias[n]
// A [M,K] bf16 row-major, Bw [N,K] bf16 row-major (both K-major).
// 128x128 tile, BK=64, 4 waves (2x2), each wave 64x64 (4x4 frags of 16x16).
// EPI 0: scatter bf16 to qkv ws [3][2][16][2048][64].  EPI 1: fp32 out [M][N].
// ---------------------------------------------------------------------------
template<int EPI>
__global__ __launch_bounds__(256) void gemm_bt(const bf16* __restrict__ A,
                                               const bf16* __restrict__ Bw,
                                               const float* __restrict__ bias,
                                               void* __restrict__ outp,
                                               int M, int N, int K) {
  __shared__ bf16 As[128 * 64];
  __shared__ bf16 Bs[128 * 64];
  const int tid  = threadIdx.x;
  const int lane = tid & 63;
  const int w    = tid >> 6;
  const int wm   = w >> 1, wn = w & 1;
  const int mBase = blockIdx.y * 128;
  const int nBase = blockIdx.x * 128;
  const int rl = lane & 15;
  const int qg = lane >> 4;
  const int srow = tid >> 3;   // 0..31
  const int schunk = tid & 7;  // 16B chunk within a 128B row

  f32x4 acc[4][4] = {};

  for (int k0 = 0; k0 < K; k0 += 64) {
    __syncthreads();
#pragma unroll
    for (int rr = 0; rr < 4; ++rr) {
      int r  = rr * 32 + srow;
      int cs = schunk ^ (r & 7);   // pre-swizzled source chunk
      gl_lds16(A  + (size_t)(mBase + r) * K + k0 + cs * 8, As + r * 64 + schunk * 8);
      gl_lds16(Bw + (size_t)(nBase + r) * K + k0 + cs * 8, Bs + r * 64 + schunk * 8);
    }
    __syncthreads();
#pragma unroll
    for (int ks = 0; ks < 2; ++ks) {
      bf16x8 af[4], bfr[4];
      const int cl = ks * 4 + qg;  // logical 16B chunk (k = cl*8)
#pragma unroll
      for (int mf = 0; mf < 4; ++mf) {
        int r = wm * 64 + mf * 16 + rl;
        af[mf] = *(const bf16x8*)(As + r * 64 + (cl ^ (r & 7)) * 8);
      }
#pragma unroll
      for (int nf = 0; nf < 4; ++nf) {
        int r = wn * 64 + nf * 16 + rl;
        bfr[nf] = *(const bf16x8*)(Bs + r * 64 + (cl ^ (r & 7)) * 8);
      }
#pragma unroll
      for (int mf = 0; mf < 4; ++mf)
#pragma unroll
        for (int nf = 0; nf < 4; ++nf)
          acc[mf][nf] = __builtin_amdgcn_mfma_f32_16x16x32_bf16(af[mf], bfr[nf],
                                                                acc[mf][nf], 0, 0, 0);
    }
  }

  // epilogue: D frag mapping col = lane&15 (n), row = (lane>>4)*4 + j (m)
#pragma unroll
  for (int mf = 0; mf < 4; ++mf) {
#pragma unroll
    for (int nf = 0; nf < 4; ++nf) {
      int n = nBase + wn * 64 + nf * 16 + rl;
      float bv = bias[n];
#pragma unroll
      for (int j = 0; j < 4; ++j) {
        int m = mBase + wm * 64 + mf * 16 + qg * 4 + j;
        float val = acc[mf][nf][j] + bv;
        if (EPI == 0) {
          int t = n >> 10, rem = n & 1023;
          int h = rem >> 6, d = rem & 63;
          int b = m >> 11, s = m & 2047;
          ((bf16*)outp)[((((size_t)t * 2 + b) * 16 + h) * 2048 + s) * 64 + d] = (bf16)val;
        } else {
          ((float*)outp)[(size_t)m * N + n] = val;
        }
      }
    }
  }
}

// ---------------------------------------------------------------------------
// Flash attention with ALiBi bias.  qkv ws layout: [3][2][16][2048][64] bf16.
// Block: 4 waves, 64 q-rows (16 per wave). KT=64 k-positions per tile.
// ---------------------------------------------------------------------------
__global__ __launch_bounds__(256) void attn_kernel(const bf16* __restrict__ qkv,
                                                   bf16* __restrict__ attout) {
  constexpr int S = 2048, D = 64, KT = 64;
  __shared__ bf16 Ks[KT * 64];       // [kpos][d], chunk-swizzled
  __shared__ bf16 Vt[64 * KT];       // [d][kpos]
  __shared__ bf16 Ps[4][16 * 72];    // per-wave P tile, padded rows

  const int tid  = threadIdx.x;
  const int lane = tid & 63;
  const int w    = tid >> 6;
  const int qt   = blockIdx.x;       // q-tile (64 rows)
  const int bh   = blockIdx.y;
  const int b = bh >> 4, h = bh & 15;
  const size_t headoff = (size_t)(b * 16 + h) * S * D;
  const size_t tstride = (size_t)2 * 16 * S * D; // 4194304
  const bf16* Qg = qkv + headoff;
  const bf16* Kg = qkv + tstride + headoff;
  const bf16* Vg = qkv + 2 * tstride + headoff;

  const int rl = lane & 15;
  const int qg = lane >> 4;
  const int srow = tid >> 3;
  const int schunk = tid & 7;

  // Q fragments in registers (row = qt*64 + w*16 + rl, k = ks*32 + qg*8)
  bf16x8 qf[2];
  {
    int row = qt * 64 + w * 16 + rl;
    qf[0] = *(const bf16x8*)(Qg + (size_t)row * 64 + qg * 8);
    qf[1] = *(const bf16x8*)(Qg + (size_t)row * 64 + 32 + qg * 8);
  }

  const float slope = exp2f(-0.5f * (float)(h + 1));
  f32x4 o[4] = {};
  float m2[4], lsum[4];
#pragma unroll
  for (int j = 0; j < 4; ++j) { m2[j] = -__builtin_inff(); lsum[j] = 0.f; }

  for (int kb = 0; kb < S; kb += KT) {
    __syncthreads();
    // stage K (swizzled global_load_lds)
#pragma unroll
    for (int rr = 0; rr < 2; ++rr) {
      int r  = rr * 32 + srow;
      int cs = schunk ^ (r & 7);
      gl_lds16(Kg + (size_t)(kb + r) * 64 + cs * 8, Ks + r * 64 + schunk * 8);
    }
    // stage V transposed: Vt[d][kpos]
#pragma unroll
    for (int rr = 0; rr < 2; ++rr) {
      int kp = rr * 32 + srow;
      bf16x8 vv = *(const bf16x8*)(Vg + (size_t)(kb + kp) * 64 + schunk * 8);
#pragma unroll
      for (int jj = 0; jj < 8; ++jj)
        Vt[(schunk * 8 + jj) * KT + kp] = vv[jj];
    }
    __syncthreads();

    // QK^T: scores 16(q) x 64(kcol) per wave
    f32x4 sc[4] = {};
#pragma unroll
    for (int cf = 0; cf < 4; ++cf) {
      int r = cf * 16 + rl;
#pragma unroll
      for (int ks = 0; ks < 2; ++ks) {
        int cl = ks * 4 + qg;
        bf16x8 kf = *(const bf16x8*)(Ks + r * 64 + (cl ^ (r & 7)) * 8);
        sc[cf] = __builtin_amdgcn_mfma_f32_16x16x32_bf16(qf[ks], kf, sc[cf], 0, 0, 0);
      }
    }

    // bias + online softmax (base-2 domain)
    float pv[4][4], mx[4], rs[4], alpha[4];
#pragma unroll
    for (int j = 0; j < 4; ++j) {
      int qi = qt * 64 + w * 16 + qg * 4 + j;
      mx[j] = -__builtin_inff();
#pragma unroll
      for (int cf = 0; cf < 4; ++cf) {
        int kj = kb + cf * 16 + rl;
        float t = sc[cf][j] * 0.125f + fminf(slope * (float)(qi - kj), 8.0f);
        pv[cf][j] = t * LOG2E;
        mx[j] = fmaxf(mx[j], pv[cf][j]);
      }
    }
#pragma unroll
    for (int off = 1; off < 16; off <<= 1)
#pragma unroll
      for (int j = 0; j < 4; ++j)
        mx[j] = fmaxf(mx[j], __shfl_xor(mx[j], off, 16));
#pragma unroll
    for (int j = 0; j < 4; ++j) {
      float mn = fmaxf(m2[j], mx[j]);
      alpha[j] = exp2f(m2[j] - mn);
      m2[j] = mn;
      rs[j] = 0.f;
    }
#pragma unroll
    for (int cf = 0; cf < 4; ++cf)
#pragma unroll
      for (int j = 0; j < 4; ++j) {
        float p = exp2f(pv[cf][j] - m2[j]);
        rs[j] += p;
        Ps[w][(qg * 4 + j) * 72 + cf * 16 + rl] = (bf16)p;
      }
#pragma unroll
    for (int off = 1; off < 16; off <<= 1)
#pragma unroll
      for (int j = 0; j < 4; ++j)
        rs[j] += __shfl_xor(rs[j], off, 16);
#pragma unroll
    for (int j = 0; j < 4; ++j)
      lsum[j] = lsum[j] * alpha[j] + rs[j];
#pragma unroll
    for (int dg = 0; dg < 4; ++dg)
#pragma unroll
      for (int j = 0; j < 4; ++j)
        o[dg][j] *= alpha[j];

    __builtin_amdgcn_wave_barrier();

    // PV: O[16q][64d] += P[16q][64k] x V[64k][64d]
#pragma unroll
    for (int kc = 0; kc < 2; ++kc) {
      bf16x8 pa = *(const bf16x8*)(&Ps[w][rl * 72 + kc * 32 + qg * 8]);
#pragma unroll
      for (int dg = 0; dg < 4; ++dg) {
        bf16x8 vb = *(const bf16x8*)(Vt + (dg * 16 + rl) * 64 + kc * 32 + qg * 8);
        o[dg] = __builtin_amdgcn_mfma_f32_16x16x32_bf16(pa, vb, o[dg], 0, 0, 0);
      }
    }
  }

  // write O / l  -> attout [b*2048+row][h*64+col] bf16
#pragma unroll
  for (int dg = 0; dg < 4; ++dg)
#pragma unroll
    for (int j = 0; j < 4; ++j) {
      int row = qt * 64 + w * 16 + qg * 4 + j;
      int col = h * 64 + dg * 16 + rl;
      attout[((size_t)b * 2048 + row) * 1024 + col] = (bf16)(o[dg][j] / lsum[j]);
    }
}

// ---------------------------------------------------------------------------
extern "C" void kernel_launch(void* const* d_in, const int* in_sizes, int n_in,
                              void* d_out, int out_size, void* d_ws, size_t ws_size,
                              hipStream_t stream) {
  const float* x  = (const float*)d_in[0];   // [2,2048,1024]
  const float* w1 = (const float*)d_in[1];   // [3072,1024]
  const float* b1 = (const float*)d_in[2];   // [3072]
  const float* w2 = (const float*)d_in[3];   // [1024,1024]
  const float* b2 = (const float*)d_in[4];   // [1024]
  float* out = (float*)d_out;

  char* ws = (char*)d_ws;
  bf16* xb    = (bf16*)(ws);                       // 4194304  elems
  bf16* w1b   = (bf16*)(ws + 8388608);             // 3145728
  bf16* w2b   = (bf16*)(ws + 14680064);            // 1048576
  bf16* qkvb  = (bf16*)(ws + 16777216);            // 12582912  [3][2][16][2048][64]
  bf16* attnb = (bf16*)(ws + 41943040);            // 4194304   [4096][1024]

  cvt3_kernel<<<2048, 256, 0, stream>>>(x, w1, w2, xb, w1b, w2b);
  gemm_bt<0><<<dim3(24, 32), 256, 0, stream>>>(xb, w1b, b1, (void*)qkvb, 4096, 3072, 1024);
  attn_kernel<<<dim3(32, 32), 256, 0, stream>>>(qkvb, attnb);
  gemm_bt<1><<<dim3(8, 32), 256, 0, stream>>>(attnb, w2b, b2, (void*)out, 4096, 1024, 1024);
}

// Round 2
// 170.960 us; speedup vs baseline: 1.5325x; 1.5325x over previous
//
#include <hip/hip_runtime.h>
#include <hip/hip_bf16.h>

typedef __bf16 bf16;
typedef __bf16 bf16x8 __attribute__((ext_vector_type(8)));
typedef __bf16 bf16x4 __attribute__((ext_vector_type(4)));
typedef float  f32x4  __attribute__((ext_vector_type(4)));

#define LOG2E 1.44269504088896340736f

// B=2, S=2048, C=1024, H=16, D=64, M=B*S=4096
// qkv ws layout: Q [2][16][2048][64] | K [2][16][2048][64] | V^T [2][16][64][2048]

__device__ __forceinline__ void gl_lds16(const void* g, void* l) {
  __builtin_amdgcn_global_load_lds((__attribute__((address_space(1))) void*)g,
                                   (__attribute__((address_space(3))) void*)l,
                                   16, 0, 0);
}

// ---------------------------------------------------------------------------
__global__ void cvt3_kernel(const float* __restrict__ x,
                            const float* __restrict__ w1,
                            const float* __restrict__ w2,
                            bf16* __restrict__ xb,
                            bf16* __restrict__ w1b,
                            bf16* __restrict__ w2b) {
  const int NX = 1048576, NW1 = 786432, NW2 = 262144; // float4 quads
  const int total = NX + NW1 + NW2;
  int i = blockIdx.x * blockDim.x + threadIdx.x;
  const int stride = gridDim.x * blockDim.x;
  for (; i < total; i += stride) {
    const float* s; bf16* d; int j;
    if (i < NX)            { s = x;  d = xb;  j = i; }
    else if (i < NX + NW1) { s = w1; d = w1b; j = i - NX; }
    else                   { s = w2; d = w2b; j = i - NX - NW1; }
    f32x4 v = ((const f32x4*)s)[j];
    bf16x4 o;
    o[0] = (bf16)v[0]; o[1] = (bf16)v[1]; o[2] = (bf16)v[2]; o[3] = (bf16)v[3];
    ((bf16x4*)d)[j] = o;
  }
}

// ---------------------------------------------------------------------------
// GEMM: C[m][n] = sum_k A[m][k]*Bw[n][k] + bias[n]; 128x128 tile, BK=64, 4 waves.
// EPI 0: scatter to qkv ws (Q pre-scaled by 0.125*LOG2E, V transposed per head).
// EPI 1: fp32 out [M][N].
// ---------------------------------------------------------------------------
template<int EPI>
__global__ __launch_bounds__(256) void gemm_bt(const bf16* __restrict__ A,
                                               const bf16* __restrict__ Bw,
                                               const float* __restrict__ bias,
                                               void* __restrict__ outp,
                                               int M, int N, int K) {
  __shared__ bf16 As[128 * 64];
  __shared__ bf16 Bs[128 * 64];
  const int tid  = threadIdx.x;
  const int lane = tid & 63;
  const int w    = tid >> 6;
  const int wm   = w >> 1, wn = w & 1;
  const int mBase = blockIdx.y * 128;
  const int nBase = blockIdx.x * 128;
  const int rl = lane & 15;
  const int qg = lane >> 4;
  const int srow = tid >> 3;
  const int schunk = tid & 7;

  f32x4 acc[4][4] = {};

  for (int k0 = 0; k0 < K; k0 += 64) {
    __syncthreads();
#pragma unroll
    for (int rr = 0; rr < 4; ++rr) {
      int r  = rr * 32 + srow;
      int cs = schunk ^ (r & 7);
      gl_lds16(A  + (size_t)(mBase + r) * K + k0 + cs * 8, As + r * 64 + schunk * 8);
      gl_lds16(Bw + (size_t)(nBase + r) * K + k0 + cs * 8, Bs + r * 64 + schunk * 8);
    }
    __syncthreads();
#pragma unroll
    for (int ks = 0; ks < 2; ++ks) {
      bf16x8 af[4], bfr[4];
      const int cl = ks * 4 + qg;
#pragma unroll
      for (int mf = 0; mf < 4; ++mf) {
        int r = wm * 64 + mf * 16 + rl;
        af[mf] = *(const bf16x8*)(As + r * 64 + (cl ^ (r & 7)) * 8);
      }
#pragma unroll
      for (int nf = 0; nf < 4; ++nf) {
        int r = wn * 64 + nf * 16 + rl;
        bfr[nf] = *(const bf16x8*)(Bs + r * 64 + (cl ^ (r & 7)) * 8);
      }
#pragma unroll
      for (int mf = 0; mf < 4; ++mf)
#pragma unroll
        for (int nf = 0; nf < 4; ++nf)
          acc[mf][nf] = __builtin_amdgcn_mfma_f32_16x16x32_bf16(af[mf], bfr[nf],
                                                                acc[mf][nf], 0, 0, 0);
    }
  }

#pragma unroll
  for (int mf = 0; mf < 4; ++mf) {
#pragma unroll
    for (int nf = 0; nf < 4; ++nf) {
      int n = nBase + wn * 64 + nf * 16 + rl;
      float bv = bias[n];
#pragma unroll
      for (int j = 0; j < 4; ++j) {
        int m = mBase + wm * 64 + mf * 16 + qg * 4 + j;
        float val = acc[mf][nf][j] + bv;
        if (EPI == 0) {
          int t = n >> 10, rem = n & 1023;
          int h = rem >> 6, d = rem & 63;
          int b = m >> 11, s = m & 2047;
          bf16* q = (bf16*)outp;
          size_t hb = (size_t)(b * 16 + h);
          if (t == 0) {
            q[(hb * 2048 + s) * 64 + d] = (bf16)(val * (0.125f * LOG2E));
          } else if (t == 1) {
            q[4194304 + (hb * 2048 + s) * 64 + d] = (bf16)val;
          } else {
            q[8388608 + (hb * 64 + d) * 2048 + s] = (bf16)val;
          }
        } else {
          ((float*)outp)[(size_t)m * N + n] = val;
        }
      }
    }
  }
}

// ---------------------------------------------------------------------------
// Flash attention with ALiBi. 4 waves x 16 q-rows, KT=64 per tile.
// K tile [kp][d] swizzled; V^T tile [d][kp] swizzled (+ ones row for lsum).
// ---------------------------------------------------------------------------
__global__ __launch_bounds__(256) void attn_kernel(const bf16* __restrict__ qkv,
                                                   bf16* __restrict__ attout) {
  constexpr int S = 2048;
  __shared__ bf16 Ks[64 * 64];
  __shared__ bf16 Vt[80 * 64];      // rows 0..63 V^T, row 64 ones, 65..79 zeros
  __shared__ bf16 Ps[4][16 * 72];

  const int tid  = threadIdx.x;
  const int lane = tid & 63;
  const int w    = tid >> 6;
  const int qt   = blockIdx.x;
  const int bh   = blockIdx.y;
  const int h    = bh & 15;
  const size_t headoff = (size_t)bh * 131072;
  const bf16* Qg = qkv + headoff;
  const bf16* Kg = qkv + 4194304 + headoff;
  const bf16* Vg = qkv + 8388608 + headoff;   // [64][2048]

  const int rl = lane & 15;
  const int qg = lane >> 4;
  const int srow = tid >> 3;
  const int schunk = tid & 7;

  // static rows of Vt: row 64 = 1.0 (lsum column), rows 65..79 = 0
  for (int i = tid; i < 16 * 64; i += 256)
    Vt[64 * 64 + i] = (i < 64) ? (bf16)1.0f : (bf16)0.0f;

  // Q fragments (pre-scaled by 0.125*LOG2E in GEMM epilogue)
  bf16x8 qf[2];
  {
    int row = qt * 64 + w * 16 + rl;
    qf[0] = *(const bf16x8*)(Qg + (size_t)row * 64 + qg * 8);
    qf[1] = *(const bf16x8*)(Qg + (size_t)row * 64 + 32 + qg * 8);
  }

  const float slope2 = exp2f(-0.5f * (float)(h + 1)) * LOG2E;
  const float MB2 = 8.0f * LOG2E;
  float arow[4], bcol[4];
#pragma unroll
  for (int j = 0; j < 4; ++j)
    arow[j] = slope2 * (float)(qt * 64 + w * 16 + qg * 4 + j);
#pragma unroll
  for (int cf = 0; cf < 4; ++cf)
    bcol[cf] = slope2 * (float)(cf * 16 + rl);
  const float kstep = slope2 * 64.0f;

  f32x4 o[5] = {};                  // o[4] = ones-column accumulator (lsum)
  float m2[4];
#pragma unroll
  for (int j = 0; j < 4; ++j) m2[j] = -__builtin_inff();

  for (int kb = 0; kb < S; kb += 64) {
    __syncthreads();
#pragma unroll
    for (int rr = 0; rr < 2; ++rr) {
      int r  = rr * 32 + srow;
      int cs = schunk ^ (r & 7);
      gl_lds16(Kg + (size_t)(kb + r) * 64 + cs * 8, Ks + r * 64 + schunk * 8);
      gl_lds16(Vg + (size_t)r * 2048 + kb + cs * 8, Vt + r * 64 + schunk * 8);
    }
    __syncthreads();

    // QK^T: 16(q) x 64(k) per wave
    f32x4 sc[4] = {};
#pragma unroll
    for (int cf = 0; cf < 4; ++cf) {
      int r = cf * 16 + rl;
#pragma unroll
      for (int ks = 0; ks < 2; ++ks) {
        int cl = ks * 4 + qg;
        bf16x8 kf = *(const bf16x8*)(Ks + r * 64 + (cl ^ (r & 7)) * 8);
        sc[cf] = __builtin_amdgcn_mfma_f32_16x16x32_bf16(qf[ks], kf, sc[cf], 0, 0, 0);
      }
    }

    // bias + online softmax (base-2)
    float pv[4][4], mx[4];
#pragma unroll
    for (int j = 0; j < 4; ++j) mx[j] = -__builtin_inff();
#pragma unroll
    for (int cf = 0; cf < 4; ++cf)
#pragma unroll
      for (int j = 0; j < 4; ++j) {
        float t = sc[cf][j] + fminf(arow[j] - bcol[cf], MB2);
        pv[cf][j] = t;
        mx[j] = fmaxf(mx[j], t);
      }
#pragma unroll
    for (int off = 1; off < 16; off <<= 1)
#pragma unroll
      for (int j = 0; j < 4; ++j)
        mx[j] = fmaxf(mx[j], __shfl_xor(mx[j], off, 16));

    // defer-max: rescale only if max grew by more than 8 (base-2)
    float g = fmaxf(fmaxf(mx[0] - m2[0], mx[1] - m2[1]),
                    fmaxf(mx[2] - m2[2], mx[3] - m2[3]));
    g = fmaxf(g, __shfl_xor(g, 16));
    g = fmaxf(g, __shfl_xor(g, 32));
    if (g > 8.0f) {
#pragma unroll
      for (int j = 0; j < 4; ++j) {
        float mn = fmaxf(m2[j], mx[j]);
        float alpha = exp2f(m2[j] - mn);
        m2[j] = mn;
#pragma unroll
        for (int dg = 0; dg < 5; ++dg)
          o[dg][j] *= alpha;
      }
    }

#pragma unroll
    for (int cf = 0; cf < 4; ++cf)
#pragma unroll
      for (int j = 0; j < 4; ++j) {
        float p = exp2f(pv[cf][j] - m2[j]);
        Ps[w][(qg * 4 + j) * 72 + cf * 16 + rl] = (bf16)p;
      }

    __builtin_amdgcn_wave_barrier();

    // PV (+ ones column): O[16q][64d+lsum] += P[16q][64k] x Vt^T
#pragma unroll
    for (int kc = 0; kc < 2; ++kc) {
      bf16x8 pa = *(const bf16x8*)(&Ps[w][rl * 72 + kc * 32 + qg * 8]);
#pragma unroll
      for (int dg = 0; dg < 5; ++dg) {
        int row = dg * 16 + rl;
        bf16x8 vb = *(const bf16x8*)(Vt + row * 64 + ((kc * 4 + qg) ^ (row & 7)) * 8);
        o[dg] = __builtin_amdgcn_mfma_f32_16x16x32_bf16(pa, vb, o[dg], 0, 0, 0);
      }
    }

#pragma unroll
    for (int cf = 0; cf < 4; ++cf) bcol[cf] += kstep;
  }

  // lsum lives in o[4] at col 64 (lanes rl==0); broadcast within 16-group
  float inv[4];
#pragma unroll
  for (int j = 0; j < 4; ++j)
    inv[j] = 1.0f / __shfl(o[4][j], lane & 48);

  const int b = bh >> 4;
#pragma unroll
  for (int dg = 0; dg < 4; ++dg)
#pragma unroll
    for (int j = 0; j < 4; ++j) {
      int row = qt * 64 + w * 16 + qg * 4 + j;
      int col = h * 64 + dg * 16 + rl;
      attout[((size_t)b * 2048 + row) * 1024 + col] = (bf16)(o[dg][j] * inv[j]);
    }
}

// ---------------------------------------------------------------------------
extern "C" void kernel_launch(void* const* d_in, const int* in_sizes, int n_in,
                              void* d_out, int out_size, void* d_ws, size_t ws_size,
                              hipStream_t stream) {
  const float* x  = (const float*)d_in[0];
  const float* w1 = (const float*)d_in[1];
  const float* b1 = (const float*)d_in[2];
  const float* w2 = (const float*)d_in[3];
  const float* b2 = (const float*)d_in[4];
  float* out = (float*)d_out;

  char* ws = (char*)d_ws;
  bf16* xb    = (bf16*)(ws);
  bf16* w1b   = (bf16*)(ws + 8388608);
  bf16* w2b   = (bf16*)(ws + 14680064);
  bf16* qkvb  = (bf16*)(ws + 16777216);   // Q | K | V^T sections
  bf16* attnb = (bf16*)(ws + 41943040);

  cvt3_kernel<<<2048, 256, 0, stream>>>(x, w1, w2, xb, w1b, w2b);
  gemm_bt<0><<<dim3(24, 32), 256, 0, stream>>>(xb, w1b, b1, (void*)qkvb, 4096, 3072, 1024);
  attn_kernel<<<dim3(32, 32), 256, 0, stream>>>(qkvb, attnb);
  gemm_bt<1><<<dim3(8, 32), 256, 0, stream>>>(attnb, w2b, b2, (void*)out, 4096, 1024, 1024);
}

// Round 3
// 168.379 us; speedup vs baseline: 1.5560x; 1.0153x over previous
//
#include <hip/hip_runtime.h>
#include <hip/hip_bf16.h>

typedef __bf16 bf16;
typedef __bf16 bf16x8 __attribute__((ext_vector_type(8)));
typedef __bf16 bf16x4 __attribute__((ext_vector_type(4)));
typedef float  f32x4  __attribute__((ext_vector_type(4)));
typedef short  s16x4  __attribute__((ext_vector_type(4)));

#define LOG2E 1.44269504088896340736f

// B=2, S=2048, C=1024, H=16, D=64, M=B*S=4096
// qkv ws layout: Q [2][16][2048][64] | K [2][16][2048][64] | V^T [2][16][64][2048]

__device__ __forceinline__ void gl_lds16(const void* g, void* l) {
  __builtin_amdgcn_global_load_lds((__attribute__((address_space(1))) void*)g,
                                   (__attribute__((address_space(3))) void*)l,
                                   16, 0, 0);
}

#if __has_builtin(__builtin_amdgcn_mfma_f32_16x16x16bf16_1k)
__device__ __forceinline__ f32x4 mfma16(s16x4 a, s16x4 b, f32x4 c) {
  return __builtin_amdgcn_mfma_f32_16x16x16bf16_1k(a, b, c, 0, 0, 0);
}
#else
__device__ __forceinline__ f32x4 mfma16(s16x4 a, s16x4 b, f32x4 c) {
  f32x4 d;
  asm volatile("v_mfma_f32_16x16x16_bf16 %0, %1, %2, %3\n\ts_nop 7\n\ts_nop 3"
               : "=v"(d) : "v"(a), "v"(b), "v"(c));
  return d;
}
#endif

__device__ __forceinline__ s16x4 as_s16x4(bf16x4 v) {
  union { bf16x4 h; s16x4 s; } u; u.h = v; return u.s;
}

// ---------------------------------------------------------------------------
__global__ void cvt3_kernel(const float* __restrict__ x,
                            const float* __restrict__ w1,
                            const float* __restrict__ w2,
                            bf16* __restrict__ xb,
                            bf16* __restrict__ w1b,
                            bf16* __restrict__ w2b) {
  const int NX = 1048576, NW1 = 786432, NW2 = 262144; // float4 quads
  const int total = NX + NW1 + NW2;
  int i = blockIdx.x * blockDim.x + threadIdx.x;
  const int stride = gridDim.x * blockDim.x;
  for (; i < total; i += stride) {
    const float* s; bf16* d; int j;
    if (i < NX)            { s = x;  d = xb;  j = i; }
    else if (i < NX + NW1) { s = w1; d = w1b; j = i - NX; }
    else                   { s = w2; d = w2b; j = i - NX - NW1; }
    f32x4 v = ((const f32x4*)s)[j];
    bf16x4 o;
    o[0] = (bf16)v[0]; o[1] = (bf16)v[1]; o[2] = (bf16)v[2]; o[3] = (bf16)v[3];
    ((bf16x4*)d)[j] = o;
  }
}

// ---------------------------------------------------------------------------
// GEMM: C[m][n] = sum_k A[m][k]*Bw[n][k] + bias[n]; 128x128 tile, BK=64, 4 waves.
// EPI 0: scatter to qkv ws (Q pre-scaled by 0.125*LOG2E, V transposed per head).
// EPI 1: fp32 out [M][N].
// ---------------------------------------------------------------------------
template<int EPI>
__global__ __launch_bounds__(256) void gemm_bt(const bf16* __restrict__ A,
                                               const bf16* __restrict__ Bw,
                                               const float* __restrict__ bias,
                                               void* __restrict__ outp,
                                               int M, int N, int K) {
  __shared__ bf16 As[128 * 64];
  __shared__ bf16 Bs[128 * 64];
  const int tid  = threadIdx.x;
  const int lane = tid & 63;
  const int w    = tid >> 6;
  const int wm   = w >> 1, wn = w & 1;
  const int mBase = blockIdx.y * 128;
  const int nBase = blockIdx.x * 128;
  const int rl = lane & 15;
  const int qg = lane >> 4;
  const int srow = tid >> 3;
  const int schunk = tid & 7;

  f32x4 acc[4][4] = {};

  for (int k0 = 0; k0 < K; k0 += 64) {
    __syncthreads();
#pragma unroll
    for (int rr = 0; rr < 4; ++rr) {
      int r  = rr * 32 + srow;
      int cs = schunk ^ (r & 7);
      gl_lds16(A  + (size_t)(mBase + r) * K + k0 + cs * 8, As + r * 64 + schunk * 8);
      gl_lds16(Bw + (size_t)(nBase + r) * K + k0 + cs * 8, Bs + r * 64 + schunk * 8);
    }
    __syncthreads();
#pragma unroll
    for (int ks = 0; ks < 2; ++ks) {
      bf16x8 af[4], bfr[4];
      const int cl = ks * 4 + qg;
#pragma unroll
      for (int mf = 0; mf < 4; ++mf) {
        int r = wm * 64 + mf * 16 + rl;
        af[mf] = *(const bf16x8*)(As + r * 64 + (cl ^ (r & 7)) * 8);
      }
#pragma unroll
      for (int nf = 0; nf < 4; ++nf) {
        int r = wn * 64 + nf * 16 + rl;
        bfr[nf] = *(const bf16x8*)(Bs + r * 64 + (cl ^ (r & 7)) * 8);
      }
#pragma unroll
      for (int mf = 0; mf < 4; ++mf)
#pragma unroll
        for (int nf = 0; nf < 4; ++nf)
          acc[mf][nf] = __builtin_amdgcn_mfma_f32_16x16x32_bf16(af[mf], bfr[nf],
                                                                acc[mf][nf], 0, 0, 0);
    }
  }

#pragma unroll
  for (int mf = 0; mf < 4; ++mf) {
#pragma unroll
    for (int nf = 0; nf < 4; ++nf) {
      int n = nBase + wn * 64 + nf * 16 + rl;
      float bv = bias[n];
#pragma unroll
      for (int j = 0; j < 4; ++j) {
        int m = mBase + wm * 64 + mf * 16 + qg * 4 + j;
        float val = acc[mf][nf][j] + bv;
        if (EPI == 0) {
          int t = n >> 10, rem = n & 1023;
          int h = rem >> 6, d = rem & 63;
          int b = m >> 11, s = m & 2047;
          bf16* q = (bf16*)outp;
          size_t hb = (size_t)(b * 16 + h);
          if (t == 0) {
            q[(hb * 2048 + s) * 64 + d] = (bf16)(val * (0.125f * LOG2E));
          } else if (t == 1) {
            q[4194304 + (hb * 2048 + s) * 64 + d] = (bf16)val;
          } else {
            q[8388608 + (hb * 64 + d) * 2048 + s] = (bf16)val;
          }
        } else {
          ((float*)outp)[(size_t)m * N + n] = val;
        }
      }
    }
  }
}

// ---------------------------------------------------------------------------
// Flash attention with ALiBi. 4 waves x 16 q-rows, KT=64.
// Swapped QK^T (mfma(K,Q)) -> per-lane row-local softmax -> in-register P
// -> PV via 16x16x16 MFMA against swizzled V^T tile (+ones rows for lsum).
// ---------------------------------------------------------------------------
__global__ __launch_bounds__(256) void attn_kernel(const bf16* __restrict__ qkv,
                                                   bf16* __restrict__ attout) {
  constexpr int S = 2048;
  __shared__ bf16 Ks[64 * 64];
  __shared__ bf16 Vt[80 * 64];      // rows 0..63 V^T tile; rows 64..79 all 1.0

  const int tid  = threadIdx.x;
  const int lane = tid & 63;
  const int w    = tid >> 6;
  // XCD-aware swizzle: cluster each head's q-tiles on one XCD (id%8 = XCD)
  const int id = blockIdx.x;
  const int bh = (id & 7) * 4 + ((id >> 3) & 3);
  const int qt = id >> 5;
  const int h  = bh & 15;
  const size_t headoff = (size_t)bh * 131072;
  const bf16* Qg = qkv + headoff;
  const bf16* Kg = qkv + 4194304 + headoff;
  const bf16* Vg = qkv + 8388608 + headoff;   // [64][2048]

  const int rl = lane & 15;
  const int qg = lane >> 4;
  const int srow = tid >> 3;
  const int schunk = tid & 7;

  // ones rows (lsum block): rows 64..79 = 1.0 everywhere (swizzle-invariant)
  for (int i = tid; i < 16 * 64; i += 256)
    Vt[64 * 64 + i] = (bf16)1.0f;

  // Q fragments (pre-scaled by 0.125*LOG2E); lane's q-row = qt*64 + w*16 + rl
  const int qrow = qt * 64 + w * 16 + rl;
  bf16x8 qf[2];
  qf[0] = *(const bf16x8*)(Qg + (size_t)qrow * 64 + qg * 8);
  qf[1] = *(const bf16x8*)(Qg + (size_t)qrow * 64 + 32 + qg * 8);

  // hoisted LDS offsets (element units), constant across k-tiles
  int koff[4][2];
#pragma unroll
  for (int cf = 0; cf < 4; ++cf) {
    int r = cf * 16 + rl, r7 = r & 7;
#pragma unroll
    for (int ks = 0; ks < 2; ++ks)
      koff[cf][ks] = r * 64 + (((ks * 4 + qg) ^ r7) << 3);
  }
  int voff[4][5];
#pragma unroll
  for (int dg = 0; dg < 5; ++dg) {
    int row = dg * 16 + rl, r7 = row & 7;
#pragma unroll
    for (int cf = 0; cf < 4; ++cf)
      voff[cf][dg] = row * 64 + ((((cf << 1) + (qg >> 1)) ^ r7) << 3) + ((qg & 1) << 2);
  }

  // hoisted stage pointers
  const int cs8 = (schunk ^ (srow & 7)) * 8;
  const bf16* ksrc = Kg + (size_t)srow * 64 + cs8;
  const bf16* vsrc = Vg + (size_t)srow * 2048 + cs8;
  bf16* kdst = Ks + srow * 64 + schunk * 8;
  bf16* vdst = Vt + srow * 64 + schunk * 8;

  // softmax state (base-2 domain, m2 folded into basep/Mm; m2 init = 0)
  const float slope2 = exp2f(-0.5f * (float)(h + 1)) * LOG2E;
  const float nslope = -slope2;
  const float kstep  = slope2 * 64.0f;
  float basep = slope2 * (float)(qrow - qg * 4);   // slope2*(q - kb - qg*4) - m2
  float Mm    = 8.0f * LOG2E;                      // MAX_BIAS*LOG2E - m2

  f32x4 o[5] = {};                  // o[4] = lsum (ones block)

  for (int kt = 0; kt < S / 64; ++kt) {
    __syncthreads();
    gl_lds16(ksrc,             kdst);
    gl_lds16(ksrc + 32 * 64,   kdst + 32 * 64);
    gl_lds16(vsrc,             vdst);
    gl_lds16(vsrc + 32 * 2048, vdst + 32 * 64);
    ksrc += 64 * 64; vsrc += 64;
    __syncthreads();

    // swapped QK^T: sc[cf][j] = score(q=qrow, k = kb + cf*16 + qg*4 + j)
    f32x4 sc[4] = {};
#pragma unroll
    for (int cf = 0; cf < 4; ++cf)
#pragma unroll
      for (int ks = 0; ks < 2; ++ks) {
        bf16x8 kf = *(const bf16x8*)(Ks + koff[cf][ks]);
        sc[cf] = __builtin_amdgcn_mfma_f32_16x16x32_bf16(kf, qf[ks], sc[cf], 0, 0, 0);
      }

    // bias (m2 pre-folded) + row max (lane-local + 2 shfl)
    float t[4][4];
#pragma unroll
    for (int cf = 0; cf < 4; ++cf)
#pragma unroll
      for (int j = 0; j < 4; ++j)
        t[cf][j] = sc[cf][j] + fminf(__builtin_fmaf(nslope, (float)(cf * 16 + j), basep), Mm);

    float mxa = fmaxf(fmaxf(t[0][0], t[0][1]), fmaxf(t[0][2], t[0][3]));
    float mxb = fmaxf(fmaxf(t[1][0], t[1][1]), fmaxf(t[1][2], t[1][3]));
    float mxc = fmaxf(fmaxf(t[2][0], t[2][1]), fmaxf(t[2][2], t[2][3]));
    float mxd = fmaxf(fmaxf(t[3][0], t[3][1]), fmaxf(t[3][2], t[3][3]));
    float mx = fmaxf(fmaxf(mxa, mxb), fmaxf(mxc, mxd));
    mx = fmaxf(mx, __shfl_xor(mx, 16));
    mx = fmaxf(mx, __shfl_xor(mx, 32));

    bf16x4 pav[4];
    if (__any(mx > 8.0f)) {
      // rescale: shift own row's reference by d = max(mx, 0)
      float d = fmaxf(mx, 0.0f);
      basep -= d; Mm -= d;
      float alpha = exp2f(-d);
      float av[4];
#pragma unroll
      for (int j = 0; j < 4; ++j)
        av[j] = __shfl(alpha, qg * 4 + j);
#pragma unroll
      for (int dg = 0; dg < 5; ++dg)
#pragma unroll
        for (int j = 0; j < 4; ++j)
          o[dg][j] *= av[j];
#pragma unroll
      for (int cf = 0; cf < 4; ++cf)
#pragma unroll
        for (int j = 0; j < 4; ++j)
          pav[cf][j] = (bf16)exp2f(t[cf][j] - d);
    } else {
#pragma unroll
      for (int cf = 0; cf < 4; ++cf)
#pragma unroll
        for (int j = 0; j < 4; ++j)
          pav[cf][j] = (bf16)exp2f(t[cf][j]);
    }

    // PV: O[q][d] += P[q][k] V[k][d] via 16x16x16 (A = in-register P frags)
#pragma unroll
    for (int cf = 0; cf < 4; ++cf) {
      s16x4 pa = as_s16x4(pav[cf]);
#pragma unroll
      for (int dg = 0; dg < 5; ++dg) {
        s16x4 vb = *(const s16x4*)(Vt + voff[cf][dg]);
        o[dg] = mfma16(pa, vb, o[dg]);
      }
    }

    basep -= kstep;
  }

  // epilogue: D layout row = qg*4+j, col = rl; lsum already per-row in o[4]
  float inv[4];
#pragma unroll
  for (int j = 0; j < 4; ++j)
    inv[j] = 1.0f / o[4][j];

  const int b = bh >> 4;
#pragma unroll
  for (int dg = 0; dg < 4; ++dg)
#pragma unroll
    for (int j = 0; j < 4; ++j) {
      int row = qt * 64 + w * 16 + qg * 4 + j;
      int col = h * 64 + dg * 16 + rl;
      attout[((size_t)b * 2048 + row) * 1024 + col] = (bf16)(o[dg][j] * inv[j]);
    }
}

// ---------------------------------------------------------------------------
extern "C" void kernel_launch(void* const* d_in, const int* in_sizes, int n_in,
                              void* d_out, int out_size, void* d_ws, size_t ws_size,
                              hipStream_t stream) {
  const float* x  = (const float*)d_in[0];
  const float* w1 = (const float*)d_in[1];
  const float* b1 = (const float*)d_in[2];
  const float* w2 = (const float*)d_in[3];
  const float* b2 = (const float*)d_in[4];
  float* out = (float*)d_out;

  char* ws = (char*)d_ws;
  bf16* xb    = (bf16*)(ws);
  bf16* w1b   = (bf16*)(ws + 8388608);
  bf16* w2b   = (bf16*)(ws + 14680064);
  bf16* qkvb  = (bf16*)(ws + 16777216);   // Q | K | V^T sections
  bf16* attnb = (bf16*)(ws + 41943040);

  cvt3_kernel<<<2048, 256, 0, stream>>>(x, w1, w2, xb, w1b, w2b);
  gemm_bt<0><<<dim3(24, 32), 256, 0, stream>>>(xb, w1b, b1, (void*)qkvb, 4096, 3072, 1024);
  attn_kernel<<<1024, 256, 0, stream>>>(qkvb, attnb);
  gemm_bt<1><<<dim3(8, 32), 256, 0, stream>>>(attnb, w2b, b2, (void*)out, 4096, 1024, 1024);
}